// Round 1
// baseline (899.900 us; speedup 1.0000x reference)
//
#include <hip/hip_runtime.h>
#include <math.h>

// ---------------------------------------------------------------------------
// NSA attention forward, fp32 baseline (v1 — correctness first).
// Pipeline: proj(Q) + proj(KVx6) -> RoPE -> compress -> cmp-attn(+p_grp+top16)
//           -> sel-attn / win-attn (flash-style) -> gate MLP -> combine -> out proj
// ---------------------------------------------------------------------------

#define S_    1536
#define DIM_  1024
#define G_    2
#define HPG_  8
#define H_    16
#define DK_   64
#define NC_   95
#define NB_   24
#define NSEL_ 16
#define WINW_ 512
#define SCALE_ 0.125f

// ======================= generic GEMM: C[m][n] = sum_k A[m][k]*B[n][k] ======
__global__ __launch_bounds__(256) void gemm_nt(const float* __restrict__ A,
                                               const float* __restrict__ B,
                                               float* __restrict__ C,
                                               int M, int N, int K) {
  __shared__ float As[16][68];
  __shared__ float Bs[16][68];
  int bn = blockIdx.x * 64, bm = blockIdx.y * 64;
  int t = threadIdx.x;
  int tn = (t & 15) * 4, tm = (t >> 4) * 4;
  float acc[4][4] = {};
  const float* Ab = A + (size_t)bm * K;
  const float* Bb = B + (size_t)bn * K;
  int row = t >> 2, kq = t & 3;
  for (int k0 = 0; k0 < K; k0 += 16) {
    float4 av = *reinterpret_cast<const float4*>(Ab + (size_t)row * K + k0 + kq * 4);
    float4 bv = *reinterpret_cast<const float4*>(Bb + (size_t)row * K + k0 + kq * 4);
    As[kq*4+0][row] = av.x; As[kq*4+1][row] = av.y; As[kq*4+2][row] = av.z; As[kq*4+3][row] = av.w;
    Bs[kq*4+0][row] = bv.x; Bs[kq*4+1][row] = bv.y; Bs[kq*4+2][row] = bv.z; Bs[kq*4+3][row] = bv.w;
    __syncthreads();
#pragma unroll
    for (int kk = 0; kk < 16; ++kk) {
      float4 a4 = *reinterpret_cast<const float4*>(&As[kk][tm]);
      float4 b4 = *reinterpret_cast<const float4*>(&Bs[kk][tn]);
      float av_[4] = {a4.x, a4.y, a4.z, a4.w};
      float bv_[4] = {b4.x, b4.y, b4.z, b4.w};
#pragma unroll
      for (int i = 0; i < 4; ++i)
#pragma unroll
        for (int j = 0; j < 4; ++j) acc[i][j] = fmaf(av_[i], bv_[j], acc[i][j]);
    }
    __syncthreads();
  }
#pragma unroll
  for (int i = 0; i < 4; ++i) {
    *reinterpret_cast<float4*>(C + (size_t)(bm + tm + i) * N + bn + tn) =
        make_float4(acc[i][0], acc[i][1], acc[i][2], acc[i][3]);
  }
}

// ============ fused KV projections: 6 weights, out layout [proj][S][128] ====
__global__ __launch_bounds__(256) void gemm_kv(const float* __restrict__ A,
                                               const float* __restrict__ w0, const float* __restrict__ w1,
                                               const float* __restrict__ w2, const float* __restrict__ w3,
                                               const float* __restrict__ w4, const float* __restrict__ w5,
                                               float* __restrict__ kvout, int K) {
  __shared__ float As[16][68];
  __shared__ float Bs[16][68];
  int jb = blockIdx.x;              // 0..11
  int proj = jb >> 1, nc0 = (jb & 1) * 64;
  const float* B;
  switch (proj) { case 0: B = w0; break; case 1: B = w1; break; case 2: B = w2; break;
                  case 3: B = w3; break; case 4: B = w4; break; default: B = w5; }
  float* C = kvout + (size_t)proj * (S_ * 128);
  int bm = blockIdx.y * 64;
  int t = threadIdx.x;
  int tn = (t & 15) * 4, tm = (t >> 4) * 4;
  float acc[4][4] = {};
  const float* Ab = A + (size_t)bm * K;
  const float* Bb = B + (size_t)nc0 * K;
  int row = t >> 2, kq = t & 3;
  for (int k0 = 0; k0 < K; k0 += 16) {
    float4 av = *reinterpret_cast<const float4*>(Ab + (size_t)row * K + k0 + kq * 4);
    float4 bv = *reinterpret_cast<const float4*>(Bb + (size_t)row * K + k0 + kq * 4);
    As[kq*4+0][row] = av.x; As[kq*4+1][row] = av.y; As[kq*4+2][row] = av.z; As[kq*4+3][row] = av.w;
    Bs[kq*4+0][row] = bv.x; Bs[kq*4+1][row] = bv.y; Bs[kq*4+2][row] = bv.z; Bs[kq*4+3][row] = bv.w;
    __syncthreads();
#pragma unroll
    for (int kk = 0; kk < 16; ++kk) {
      float4 a4 = *reinterpret_cast<const float4*>(&As[kk][tm]);
      float4 b4 = *reinterpret_cast<const float4*>(&Bs[kk][tn]);
      float av_[4] = {a4.x, a4.y, a4.z, a4.w};
      float bv_[4] = {b4.x, b4.y, b4.z, b4.w};
#pragma unroll
      for (int i = 0; i < 4; ++i)
#pragma unroll
        for (int j = 0; j < 4; ++j) acc[i][j] = fmaf(av_[i], bv_[j], acc[i][j]);
    }
    __syncthreads();
  }
#pragma unroll
  for (int i = 0; i < 4; ++i) {
    *reinterpret_cast<float4*>(C + (size_t)(bm + tm + i) * 128 + nc0 + tn) =
        make_float4(acc[i][0], acc[i][1], acc[i][2], acc[i][3]);
  }
}

// =========================== RoPE (in place) ================================
// buffer: [nrows][ncols], heads of 64 along cols; pos = row index.
__global__ __launch_bounds__(256) void rope_kernel(float* __restrict__ p, int ncols, int total_pairs) {
  int id = blockIdx.x * 256 + threadIdx.x;
  if (id >= total_pairs) return;
  int ppr = ncols >> 1;
  int row = id / ppr, rem = id % ppr;
  int head = rem >> 5, jj = rem & 31;
  float inv = 1.0f / powf(10000.0f, (float)jj * (1.0f / 32.0f));
  float ang = (float)row * inv;
  float sn, cs;
  sincosf(ang, &sn, &cs);
  float* q = p + (size_t)row * ncols + head * 64 + jj;
  float x1 = q[0], x2 = q[32];
  q[0]  = x1 * cs - x2 * sn;
  q[32] = x2 * cs + x1 * sn;
}

// ================== compression: mean over L=32 window, stride 16 ===========
__global__ __launch_bounds__(64) void compress_kernel(const float* __restrict__ kv,
                                                      float* __restrict__ Kcmp,
                                                      float* __restrict__ Vcmp) {
  int c = blockIdx.x, g = blockIdx.y, d = threadIdx.x;
  const float* Kc = kv + (size_t)4 * (S_ * 128);
  const float* Vc = kv + (size_t)5 * (S_ * 128);
  float sk = 0.f, sv = 0.f;
  int base = c * 16;
#pragma unroll
  for (int l = 0; l < 32; ++l) {
    int s = base + l;
    sk += Kc[(size_t)s * 128 + g * 64 + d];
    sv += Vc[(size_t)s * 128 + g * 64 + d];
  }
  Kcmp[(g * NC_ + c) * 64 + d] = sk * (1.0f / 32.0f);
  Vcmp[(g * NC_ + c) * 64 + d] = sv * (1.0f / 32.0f);
}

// ====== compressed attention + p_grp + top-16 block selection ===============
// one block per (s, g); handles all 8 heads of the group.
__global__ __launch_bounds__(256) void cmp_attn(const float* __restrict__ Q,
                                                const float* __restrict__ Kcmp,
                                                const float* __restrict__ Vcmp,
                                                float* __restrict__ Ocmp,
                                                unsigned* __restrict__ selmask) {
  int s = blockIdx.x, g = blockIdx.y;
  __shared__ float Ks[NC_][65];
  __shared__ float Vs[NC_][65];
  __shared__ float Qs[8][64];
  __shared__ float Ps[8][NC_];
  __shared__ float pg[NB_];
  int t = threadIdx.x;
  for (int j = t; j < NC_ * 64; j += 256) {
    int c = j >> 6, d = j & 63;
    Ks[c][d] = Kcmp[(g * NC_ + c) * 64 + d];
    Vs[c][d] = Vcmp[(g * NC_ + c) * 64 + d];
  }
  for (int j = t; j < 512; j += 256) {
    int hp = j >> 6, d = j & 63;
    Qs[hp][d] = Q[((size_t)(s * 16) + g * 8 + hp) * 64 + d];
  }
  __syncthreads();
  int clim = (s >= 31) ? ((s - 31) >> 4) : -1;
  if (clim > NC_ - 1) clim = NC_ - 1;
  // scores
  for (int j = t; j < 8 * NC_; j += 256) {
    int hp = j / NC_, c = j % NC_;
    float acc = 0.f;
#pragma unroll
    for (int d = 0; d < 64; ++d) acc = fmaf(Qs[hp][d], Ks[c][d], acc);
    Ps[hp][c] = acc * SCALE_;
  }
  __syncthreads();
  // softmax per head (wave w handles hp = w and w+4)
  int wave = t >> 6, lane = t & 63;
#pragma unroll
  for (int rep = 0; rep < 2; ++rep) {
    int hp = wave + rep * 4;
    float s0 = (lane <= clim) ? Ps[hp][lane] : -INFINITY;
    float s1 = (lane + 64 <= clim) ? Ps[hp][lane + 64] : -INFINITY;
    float mx = fmaxf(s0, s1);
    for (int off = 32; off; off >>= 1) mx = fmaxf(mx, __shfl_xor(mx, off));
    float e0 = (lane <= clim) ? expf(s0 - mx) : 0.f;
    float e1 = (lane + 64 <= clim) ? expf(s1 - mx) : 0.f;
    float sm = e0 + e1;
    for (int off = 32; off; off >>= 1) sm += __shfl_xor(sm, off);
    float invs = (clim >= 0) ? 1.0f / sm : 0.f;
    Ps[hp][lane] = e0 * invs;
    if (lane + 64 < NC_) Ps[hp][lane + 64] = e1 * invs;
  }
  __syncthreads();
  // O_cmp
  for (int j = t; j < 512; j += 256) {
    int hp = j >> 6, d = j & 63;
    float acc = 0.f;
    for (int c = 0; c <= clim; ++c) acc = fmaf(Ps[hp][c], Vs[c][d], acc);
    Ocmp[((size_t)(s * 16) + g * 8 + hp) * 64 + d] = acc;
  }
  // p_grp (sum over heads and chunks, overlap-weighted)
  if (t < NB_) {
    int m = t;
    float a = 0.f;
    int clo = (4 * m - 1 < 0) ? 0 : 4 * m - 1;
    int chi = (4 * m + 3 > NC_ - 1) ? NC_ - 1 : 4 * m + 3;
    for (int c = clo; c <= chi; ++c) {
      int lo = c * 16 > m * 64 ? c * 16 : m * 64;
      int hi = (c * 16 + 32) < (m * 64 + 64) ? (c * 16 + 32) : (m * 64 + 64);
      int ov = hi - lo; if (ov < 0) ov = 0;
      float w = (float)ov * (1.0f / 32.0f);
      float sh = 0.f;
#pragma unroll
      for (int hp = 0; hp < 8; ++hp) sh += Ps[hp][c];
      a = fmaf(sh, w, a);
    }
    pg[m] = a;
  }
  __syncthreads();
  // top-16 selection (ties -> lowest index, matching lax.top_k)
  if (t == 0) {
    float sc[NB_];
    int blk = s >> 6;
    for (int m = 0; m < NB_; ++m) {
      float v = pg[m] + ((m == 0 || m == blk) ? 1e6f : 0.f);
      if (s < m * 64) v = -1e9f;
      sc[m] = v;
    }
    unsigned mask = 0;
    for (int it = 0; it < NSEL_; ++it) {
      int best = 0; float bv = -INFINITY;
      for (int m = 0; m < NB_; ++m)
        if (!((mask >> m) & 1) && sc[m] > bv) { bv = sc[m]; best = m; }
      mask |= (1u << best);
    }
    selmask[s * G_ + g] = mask;
  }
}

// ============== selected / window attention (flash-style) ===================
// MODE 0: selected blocks (bitmask); MODE 1: sliding window of 512.
template <int MODE>
__global__ __launch_bounds__(256) void attn_sw(const float* __restrict__ Q,
                                               const float* __restrict__ Kbuf,
                                               const float* __restrict__ Vbuf,
                                               const unsigned* __restrict__ selmask,
                                               float* __restrict__ Out) {
  int s = blockIdx.x, g = blockIdx.y;
  __shared__ float Kt[64][65];  // transposed: Kt[d][t]
  __shared__ float Vs[64][65];  // Vs[t][d]
  __shared__ float Qs[8][64];
  __shared__ float Ps[8][64];
  int t = threadIdx.x, wave = t >> 6, lane = t & 63;
  for (int j = t; j < 512; j += 256) {
    int hp = j >> 6, d = j & 63;
    Qs[hp][d] = Q[((size_t)(s * 16) + g * 8 + hp) * 64 + d];
  }
  int hp0 = wave * 2, hp1 = wave * 2 + 1;
  float m0 = -INFINITY, m1 = -INFINITY, l0 = 0.f, l1 = 0.f, a0 = 0.f, a1 = 0.f;
  unsigned mask = 0xFFFFFFFFu;
  int lotok = 0;
  int mhi = s >> 6, mlo = 0;
  if (MODE == 0) {
    mask = selmask[s * G_ + g];
  } else {
    lotok = s - (WINW_ - 1); if (lotok < 0) lotok = 0;
    mlo = lotok >> 6;
  }
  __syncthreads();
  for (int m = mlo; m <= mhi; ++m) {
    if (MODE == 0 && !((mask >> m) & 1)) continue;
    // stage 64x64 K (transposed) and V tiles
    for (int j = t; j < 64 * 16; j += 256) {
      int tt = j >> 4, c4 = j & 15;
      size_t tok = (size_t)(m * 64 + tt);
      float4 kk = *reinterpret_cast<const float4*>(&Kbuf[tok * 128 + g * 64 + c4 * 4]);
      float4 vv = *reinterpret_cast<const float4*>(&Vbuf[tok * 128 + g * 64 + c4 * 4]);
      int d0 = c4 * 4;
      Kt[d0][tt] = kk.x; Kt[d0+1][tt] = kk.y; Kt[d0+2][tt] = kk.z; Kt[d0+3][tt] = kk.w;
      Vs[tt][d0] = vv.x; Vs[tt][d0+1] = vv.y; Vs[tt][d0+2] = vv.z; Vs[tt][d0+3] = vv.w;
    }
    __syncthreads();
    int tok = m * 64 + lane;
    bool val = (tok <= s) && (tok >= lotok);
    float sc0 = -INFINITY, sc1 = -INFINITY;
    if (val) {
      float d0 = 0.f, d1 = 0.f;
#pragma unroll
      for (int d = 0; d < 64; ++d) {
        float kv_ = Kt[d][lane];
        d0 = fmaf(Qs[hp0][d], kv_, d0);
        d1 = fmaf(Qs[hp1][d], kv_, d1);
      }
      sc0 = d0 * SCALE_; sc1 = d1 * SCALE_;
    }
    float t0 = sc0, t1 = sc1;
    for (int off = 32; off; off >>= 1) {
      t0 = fmaxf(t0, __shfl_xor(t0, off));
      t1 = fmaxf(t1, __shfl_xor(t1, off));
    }
    float mn0 = fmaxf(m0, t0), mn1 = fmaxf(m1, t1);
    float al0 = (m0 == -INFINITY) ? 0.f : expf(m0 - mn0);
    float al1 = (m1 == -INFINITY) ? 0.f : expf(m1 - mn1);
    float p0 = val ? expf(sc0 - mn0) : 0.f;
    float p1 = val ? expf(sc1 - mn1) : 0.f;
    float q0 = p0, q1 = p1;
    for (int off = 32; off; off >>= 1) {
      q0 += __shfl_xor(q0, off);
      q1 += __shfl_xor(q1, off);
    }
    l0 = l0 * al0 + q0; l1 = l1 * al1 + q1;
    m0 = mn0; m1 = mn1;
    Ps[hp0][lane] = p0; Ps[hp1][lane] = p1;
    __syncthreads();
    float acc0 = 0.f, acc1 = 0.f;
#pragma unroll
    for (int tt = 0; tt < 64; ++tt) {
      float vv = Vs[tt][lane];
      acc0 = fmaf(Ps[hp0][tt], vv, acc0);
      acc1 = fmaf(Ps[hp1][tt], vv, acc1);
    }
    a0 = a0 * al0 + acc0; a1 = a1 * al1 + acc1;
    __syncthreads();
  }
  Out[((size_t)(s * 16) + g * 8 + hp0) * 64 + lane] = a0 / l0;
  Out[((size_t)(s * 16) + g * 8 + hp1) * 64 + lane] = a1 / l1;
}

// ========================= gate MLP (per (s,g)) =============================
__global__ __launch_bounds__(256) void gate_kernel(const float* __restrict__ Q,
                                                   const float* __restrict__ w1, const float* __restrict__ b1,
                                                   const float* __restrict__ w2, const float* __restrict__ b2,
                                                   float* __restrict__ gates) {
  int id = blockIdx.x * 256 + threadIdx.x;
  if (id >= S_ * G_) return;
  int s = id / G_, g = id % G_;
  float qp[64];
#pragma unroll
  for (int d = 0; d < 64; ++d) {
    float a = 0.f;
#pragma unroll
    for (int hp = 0; hp < 8; ++hp) a += Q[((size_t)(s * 16) + g * 8 + hp) * 64 + d];
    qp[d] = a * 0.125f;
  }
  float h[32];
#pragma unroll
  for (int j = 0; j < 32; ++j) {
    float a = b1[j];
#pragma unroll
    for (int d = 0; d < 64; ++d) a = fmaf(qp[d], w1[j * 64 + d], a);
    h[j] = a / (1.0f + expf(-a));  // silu
  }
  float gg[3];
#pragma unroll
  for (int o = 0; o < 3; ++o) {
    float a = b2[o];
#pragma unroll
    for (int j = 0; j < 32; ++j) a = fmaf(h[j], w2[o * 32 + j], a);
    gg[o] = a;  // TAU = 1
  }
  float mx = fmaxf(gg[0], fmaxf(gg[1], gg[2]));
  float e0 = expf(gg[0] - mx), e1 = expf(gg[1] - mx), e2 = expf(gg[2] - mx);
  float inv = 1.0f / (e0 + e1 + e2);
  float p0 = e0 * inv, p1 = e1 * inv, p2 = e2 * inv;
  int am = (gg[0] >= gg[1] && gg[0] >= gg[2]) ? 0 : (gg[1] >= gg[2] ? 1 : 2);
  float t1 = gg[am];
  float t2 = (am == 0) ? fmaxf(gg[1], gg[2]) : (am == 1) ? fmaxf(gg[0], gg[2]) : fmaxf(gg[0], gg[1]);
  if (t1 - t2 > 50.f) {
    p0 = (am == 0) ? 1.f : 0.f; p1 = (am == 1) ? 1.f : 0.f; p2 = (am == 2) ? 1.f : 0.f;
  }
  gates[id * 3 + 0] = p0; gates[id * 3 + 1] = p1; gates[id * 3 + 2] = p2;
}

// ===================== gated combine of the three outputs ===================
__global__ __launch_bounds__(256) void combine_kernel(const float* __restrict__ Oc,
                                                      const float* __restrict__ Os,
                                                      const float* __restrict__ Ow,
                                                      const float* __restrict__ gates,
                                                      float* __restrict__ Ocomb) {
  int id = blockIdx.x * 256 + threadIdx.x;
  int e = id * 4;
  if (e >= S_ * 1024) return;
  int s = e >> 10, k = e & 1023, g = k >> 9;
  const float* gt = gates + (size_t)(s * G_ + g) * 3;
  float gc = gt[0], gs = gt[1], gw = gt[2];
  float4 c = *reinterpret_cast<const float4*>(Oc + e);
  float4 l = *reinterpret_cast<const float4*>(Os + e);
  float4 w = *reinterpret_cast<const float4*>(Ow + e);
  float4 r;
  r.x = gc * c.x + gs * l.x + gw * w.x;
  r.y = gc * c.y + gs * l.y + gw * w.y;
  r.z = gc * c.z + gs * l.z + gw * w.z;
  r.w = gc * c.w + gs * l.w + gw * w.w;
  *reinterpret_cast<float4*>(Ocomb + e) = r;
}

// ============================================================================
extern "C" void kernel_launch(void* const* d_in, const int* in_sizes, int n_in,
                              void* d_out, int out_size, void* d_ws, size_t ws_size,
                              hipStream_t stream) {
  const float* x     = (const float*)d_in[0];
  const float* W_Q   = (const float*)d_in[1];
  const float* W_Ks  = (const float*)d_in[2];
  const float* W_Vs  = (const float*)d_in[3];
  const float* W_Kw  = (const float*)d_in[4];
  const float* W_Vw  = (const float*)d_in[5];
  const float* W_Kc  = (const float*)d_in[6];
  const float* W_Vc  = (const float*)d_in[7];
  const float* W_out = (const float*)d_in[8];
  const float* fc1w  = (const float*)d_in[9];
  const float* fc1b  = (const float*)d_in[10];
  const float* fc2w  = (const float*)d_in[11];
  const float* fc2b  = (const float*)d_in[12];
  float* out = (float*)d_out;

  float* ws    = (float*)d_ws;
  float* Q     = ws;                                   // S*1024
  float* kv    = Q + (size_t)S_ * 1024;                // 6 * S*128 (Ksel,Vsel,Kwin,Vwin,Kc,Vc)
  float* Kcmp  = kv + (size_t)6 * S_ * 128;            // G*NC*64
  float* Vcmp  = Kcmp + G_ * NC_ * 64;
  float* Ocmp  = Vcmp + G_ * NC_ * 64;                 // S*1024
  float* Osel  = Ocmp + (size_t)S_ * 1024;
  float* Owin  = Osel + (size_t)S_ * 1024;
  float* gates = Owin + (size_t)S_ * 1024;             // S*G*3
  unsigned* selmask = (unsigned*)(gates + S_ * G_ * 3);
  float* Ocomb = Q;  // reuse Q after gates are done

  // projections
  gemm_nt<<<dim3(1024 / 64, S_ / 64), 256, 0, stream>>>(x, W_Q, Q, S_, 1024, 1024);
  gemm_kv<<<dim3(12, S_ / 64), 256, 0, stream>>>(x, W_Ks, W_Vs, W_Kw, W_Vw, W_Kc, W_Vc, kv, 1024);
  // RoPE: Q, K_sel, K_win, Kc
  rope_kernel<<<(S_ * 512 + 255) / 256, 256, 0, stream>>>(Q, 1024, S_ * 512);
  rope_kernel<<<(S_ * 64 + 255) / 256, 256, 0, stream>>>(kv + (size_t)0 * S_ * 128, 128, S_ * 64);
  rope_kernel<<<(S_ * 64 + 255) / 256, 256, 0, stream>>>(kv + (size_t)2 * S_ * 128, 128, S_ * 64);
  rope_kernel<<<(S_ * 64 + 255) / 256, 256, 0, stream>>>(kv + (size_t)4 * S_ * 128, 128, S_ * 64);
  // compression
  compress_kernel<<<dim3(NC_, G_), 64, 0, stream>>>(kv, Kcmp, Vcmp);
  // compressed attention + selection
  cmp_attn<<<dim3(S_, G_), 256, 0, stream>>>(Q, Kcmp, Vcmp, Ocmp, selmask);
  // selected + window attention
  attn_sw<0><<<dim3(S_, G_), 256, 0, stream>>>(Q, kv + (size_t)0 * S_ * 128,
                                               kv + (size_t)1 * S_ * 128, selmask, Osel);
  attn_sw<1><<<dim3(S_, G_), 256, 0, stream>>>(Q, kv + (size_t)2 * S_ * 128,
                                               kv + (size_t)3 * S_ * 128, selmask, Owin);
  // gates
  gate_kernel<<<(S_ * G_ + 255) / 256, 256, 0, stream>>>(Q, fc1w, fc1b, fc2w, fc2b, gates);
  // combine (overwrites Q — gate_kernel already consumed it)
  combine_kernel<<<(S_ * 1024 / 4 + 255) / 256, 256, 0, stream>>>(Ocmp, Osel, Owin, gates, Ocomb);
  // output projection
  gemm_nt<<<dim3(1024 / 64, S_ / 64), 256, 0, stream>>>(Ocomb, W_out, out, S_, 1024, 1024);
}

// Round 4
// 717.767 us; speedup vs baseline: 1.2538x; 1.2538x over previous
//
#include <hip/hip_runtime.h>
#include <math.h>

// ---------------------------------------------------------------------------
// NSA attention forward, fp32 (v2 — tiled flash attention for sel/win).
// Unchanged resubmission (rounds 2,3 hit GPUAcquisitionTimeout; no signal).
// ---------------------------------------------------------------------------

#define S_    1536
#define DIM_  1024
#define G_    2
#define HPG_  8
#define H_    16
#define DK_   64
#define NC_   95
#define NB_   24
#define NSEL_ 16
#define WINW_ 512
#define SCALE_ 0.125f
#define QT_   16

// ======================= generic GEMM: C[m][n] = sum_k A[m][k]*B[n][k] ======
__global__ __launch_bounds__(256) void gemm_nt(const float* __restrict__ A,
                                               const float* __restrict__ B,
                                               float* __restrict__ C,
                                               int M, int N, int K) {
  __shared__ float As[16][68];
  __shared__ float Bs[16][68];
  int bn = blockIdx.x * 64, bm = blockIdx.y * 64;
  int t = threadIdx.x;
  int tn = (t & 15) * 4, tm = (t >> 4) * 4;
  float acc[4][4] = {};
  const float* Ab = A + (size_t)bm * K;
  const float* Bb = B + (size_t)bn * K;
  int row = t >> 2, kq = t & 3;
  for (int k0 = 0; k0 < K; k0 += 16) {
    float4 av = *reinterpret_cast<const float4*>(Ab + (size_t)row * K + k0 + kq * 4);
    float4 bv = *reinterpret_cast<const float4*>(Bb + (size_t)row * K + k0 + kq * 4);
    As[kq*4+0][row] = av.x; As[kq*4+1][row] = av.y; As[kq*4+2][row] = av.z; As[kq*4+3][row] = av.w;
    Bs[kq*4+0][row] = bv.x; Bs[kq*4+1][row] = bv.y; Bs[kq*4+2][row] = bv.z; Bs[kq*4+3][row] = bv.w;
    __syncthreads();
#pragma unroll
    for (int kk = 0; kk < 16; ++kk) {
      float4 a4 = *reinterpret_cast<const float4*>(&As[kk][tm]);
      float4 b4 = *reinterpret_cast<const float4*>(&Bs[kk][tn]);
      float av_[4] = {a4.x, a4.y, a4.z, a4.w};
      float bv_[4] = {b4.x, b4.y, b4.z, b4.w};
#pragma unroll
      for (int i = 0; i < 4; ++i)
#pragma unroll
        for (int j = 0; j < 4; ++j) acc[i][j] = fmaf(av_[i], bv_[j], acc[i][j]);
    }
    __syncthreads();
  }
#pragma unroll
  for (int i = 0; i < 4; ++i) {
    *reinterpret_cast<float4*>(C + (size_t)(bm + tm + i) * N + bn + tn) =
        make_float4(acc[i][0], acc[i][1], acc[i][2], acc[i][3]);
  }
}

// ============ fused KV projections: 6 weights, out layout [proj][S][128] ====
__global__ __launch_bounds__(256) void gemm_kv(const float* __restrict__ A,
                                               const float* __restrict__ w0, const float* __restrict__ w1,
                                               const float* __restrict__ w2, const float* __restrict__ w3,
                                               const float* __restrict__ w4, const float* __restrict__ w5,
                                               float* __restrict__ kvout, int K) {
  __shared__ float As[16][68];
  __shared__ float Bs[16][68];
  int jb = blockIdx.x;              // 0..11
  int proj = jb >> 1, nc0 = (jb & 1) * 64;
  const float* B;
  switch (proj) { case 0: B = w0; break; case 1: B = w1; break; case 2: B = w2; break;
                  case 3: B = w3; break; case 4: B = w4; break; default: B = w5; }
  float* C = kvout + (size_t)proj * (S_ * 128);
  int bm = blockIdx.y * 64;
  int t = threadIdx.x;
  int tn = (t & 15) * 4, tm = (t >> 4) * 4;
  float acc[4][4] = {};
  const float* Ab = A + (size_t)bm * K;
  const float* Bb = B + (size_t)nc0 * K;
  int row = t >> 2, kq = t & 3;
  for (int k0 = 0; k0 < K; k0 += 16) {
    float4 av = *reinterpret_cast<const float4*>(Ab + (size_t)row * K + k0 + kq * 4);
    float4 bv = *reinterpret_cast<const float4*>(Bb + (size_t)row * K + k0 + kq * 4);
    As[kq*4+0][row] = av.x; As[kq*4+1][row] = av.y; As[kq*4+2][row] = av.z; As[kq*4+3][row] = av.w;
    Bs[kq*4+0][row] = bv.x; Bs[kq*4+1][row] = bv.y; Bs[kq*4+2][row] = bv.z; Bs[kq*4+3][row] = bv.w;
    __syncthreads();
#pragma unroll
    for (int kk = 0; kk < 16; ++kk) {
      float4 a4 = *reinterpret_cast<const float4*>(&As[kk][tm]);
      float4 b4 = *reinterpret_cast<const float4*>(&Bs[kk][tn]);
      float av_[4] = {a4.x, a4.y, a4.z, a4.w};
      float bv_[4] = {b4.x, b4.y, b4.z, b4.w};
#pragma unroll
      for (int i = 0; i < 4; ++i)
#pragma unroll
        for (int j = 0; j < 4; ++j) acc[i][j] = fmaf(av_[i], bv_[j], acc[i][j]);
    }
    __syncthreads();
  }
#pragma unroll
  for (int i = 0; i < 4; ++i) {
    *reinterpret_cast<float4*>(C + (size_t)(bm + tm + i) * 128 + nc0 + tn) =
        make_float4(acc[i][0], acc[i][1], acc[i][2], acc[i][3]);
  }
}

// =========================== RoPE (in place) ================================
__global__ __launch_bounds__(256) void rope_kernel(float* __restrict__ p, int ncols, int total_pairs) {
  int id = blockIdx.x * 256 + threadIdx.x;
  if (id >= total_pairs) return;
  int ppr = ncols >> 1;
  int row = id / ppr, rem = id % ppr;
  int head = rem >> 5, jj = rem & 31;
  float inv = 1.0f / powf(10000.0f, (float)jj * (1.0f / 32.0f));
  float ang = (float)row * inv;
  float sn, cs;
  sincosf(ang, &sn, &cs);
  float* q = p + (size_t)row * ncols + head * 64 + jj;
  float x1 = q[0], x2 = q[32];
  q[0]  = x1 * cs - x2 * sn;
  q[32] = x2 * cs + x1 * sn;
}

// ================== compression: mean over L=32 window, stride 16 ===========
__global__ __launch_bounds__(64) void compress_kernel(const float* __restrict__ kv,
                                                      float* __restrict__ Kcmp,
                                                      float* __restrict__ Vcmp) {
  int c = blockIdx.x, g = blockIdx.y, d = threadIdx.x;
  const float* Kc = kv + (size_t)4 * (S_ * 128);
  const float* Vc = kv + (size_t)5 * (S_ * 128);
  float sk = 0.f, sv = 0.f;
  int base = c * 16;
#pragma unroll
  for (int l = 0; l < 32; ++l) {
    int s = base + l;
    sk += Kc[(size_t)s * 128 + g * 64 + d];
    sv += Vc[(size_t)s * 128 + g * 64 + d];
  }
  Kcmp[(g * NC_ + c) * 64 + d] = sk * (1.0f / 32.0f);
  Vcmp[(g * NC_ + c) * 64 + d] = sv * (1.0f / 32.0f);
}

// ====== compressed attention + p_grp + top-16 block selection ===============
__global__ __launch_bounds__(256) void cmp_attn(const float* __restrict__ Q,
                                                const float* __restrict__ Kcmp,
                                                const float* __restrict__ Vcmp,
                                                float* __restrict__ Ocmp,
                                                unsigned* __restrict__ selmask) {
  int s = blockIdx.x, g = blockIdx.y;
  __shared__ float Ks[NC_][65];
  __shared__ float Vs[NC_][65];
  __shared__ float Qs[8][64];
  __shared__ float Ps[8][NC_];
  __shared__ float pg[NB_];
  int t = threadIdx.x;
  for (int j = t; j < NC_ * 64; j += 256) {
    int c = j >> 6, d = j & 63;
    Ks[c][d] = Kcmp[(g * NC_ + c) * 64 + d];
    Vs[c][d] = Vcmp[(g * NC_ + c) * 64 + d];
  }
  for (int j = t; j < 512; j += 256) {
    int hp = j >> 6, d = j & 63;
    Qs[hp][d] = Q[((size_t)(s * 16) + g * 8 + hp) * 64 + d];
  }
  __syncthreads();
  int clim = (s >= 31) ? ((s - 31) >> 4) : -1;
  if (clim > NC_ - 1) clim = NC_ - 1;
  for (int j = t; j < 8 * NC_; j += 256) {
    int hp = j / NC_, c = j % NC_;
    float acc = 0.f;
#pragma unroll
    for (int d = 0; d < 64; ++d) acc = fmaf(Qs[hp][d], Ks[c][d], acc);
    Ps[hp][c] = acc * SCALE_;
  }
  __syncthreads();
  int wave = t >> 6, lane = t & 63;
#pragma unroll
  for (int rep = 0; rep < 2; ++rep) {
    int hp = wave + rep * 4;
    float s0 = (lane <= clim) ? Ps[hp][lane] : -INFINITY;
    float s1 = (lane + 64 <= clim) ? Ps[hp][lane + 64] : -INFINITY;
    float mx = fmaxf(s0, s1);
    for (int off = 32; off; off >>= 1) mx = fmaxf(mx, __shfl_xor(mx, off));
    float e0 = (lane <= clim) ? expf(s0 - mx) : 0.f;
    float e1 = (lane + 64 <= clim) ? expf(s1 - mx) : 0.f;
    float sm = e0 + e1;
    for (int off = 32; off; off >>= 1) sm += __shfl_xor(sm, off);
    float invs = (clim >= 0) ? 1.0f / sm : 0.f;
    Ps[hp][lane] = e0 * invs;
    if (lane + 64 < NC_) Ps[hp][lane + 64] = e1 * invs;
  }
  __syncthreads();
  for (int j = t; j < 512; j += 256) {
    int hp = j >> 6, d = j & 63;
    float acc = 0.f;
    for (int c = 0; c <= clim; ++c) acc = fmaf(Ps[hp][c], Vs[c][d], acc);
    Ocmp[((size_t)(s * 16) + g * 8 + hp) * 64 + d] = acc;
  }
  if (t < NB_) {
    int m = t;
    float a = 0.f;
    int clo = (4 * m - 1 < 0) ? 0 : 4 * m - 1;
    int chi = (4 * m + 3 > NC_ - 1) ? NC_ - 1 : 4 * m + 3;
    for (int c = clo; c <= chi; ++c) {
      int lo = c * 16 > m * 64 ? c * 16 : m * 64;
      int hi = (c * 16 + 32) < (m * 64 + 64) ? (c * 16 + 32) : (m * 64 + 64);
      int ov = hi - lo; if (ov < 0) ov = 0;
      float w = (float)ov * (1.0f / 32.0f);
      float sh = 0.f;
#pragma unroll
      for (int hp = 0; hp < 8; ++hp) sh += Ps[hp][c];
      a = fmaf(sh, w, a);
    }
    pg[m] = a;
  }
  __syncthreads();
  if (t == 0) {
    float sc[NB_];
    int blk = s >> 6;
    for (int m = 0; m < NB_; ++m) {
      float v = pg[m] + ((m == 0 || m == blk) ? 1e6f : 0.f);
      if (s < m * 64) v = -1e9f;
      sc[m] = v;
    }
    unsigned mask = 0;
    for (int it = 0; it < NSEL_; ++it) {
      int best = 0; float bv = -INFINITY;
      for (int m = 0; m < NB_; ++m)
        if (!((mask >> m) & 1) && sc[m] > bv) { bv = sc[m]; best = m; }
      mask |= (1u << best);
    }
    selmask[s * G_ + g] = mask;
  }
}

// ============== fused sel/win attention, 16-query tiles, flash-style ========
// grid (S/QT, G, 2): z=0 selected-blocks mode, z=1 sliding-window mode.
// 512 threads. Thread t owns rows r0=2*(t>>3), r0+1 (same query q=t>>5) and
// token-slice (t&7)*8..+7 for QK / dim-slice (t&7)*8..+7 for PV.
__global__ __launch_bounds__(512) void attn_fused(const float* __restrict__ Qg,
                                                  const float* __restrict__ kv,
                                                  const unsigned* __restrict__ selmask,
                                                  float* __restrict__ Osel,
                                                  float* __restrict__ Owin) {
  const int tb = blockIdx.x, g = blockIdx.y, mode = blockIdx.z;
  const int s0 = tb * QT_;
  const float* Kbuf = kv + (size_t)(mode ? 2 : 0) * (S_ * 128);
  const float* Vbuf = kv + (size_t)(mode ? 3 : 1) * (S_ * 128);
  float* Out = mode ? Owin : Osel;

  __shared__ float Qs[128][68];
  __shared__ float Ps[128][68];
  __shared__ float Kt[64][68];   // transposed: Kt[d][tok]
  __shared__ float Vs[64][68];   // Vs[tok][d]
  __shared__ unsigned umasks[16];

  const int t = threadIdx.x;
  // ---- stage Q tile (128 rows x 64) ----
#pragma unroll
  for (int k = 0; k < 4; ++k) {
    int qid = t + k * 512;           // 0..2047 quads
    int row = qid >> 4, c4 = qid & 15;
    int q = row >> 3, hp = row & 7;
    float4 v = *reinterpret_cast<const float4*>(
        Qg + ((size_t)(s0 + q) * 16 + g * 8 + hp) * 64 + c4 * 4);
    *reinterpret_cast<float4*>(&Qs[row][c4 * 4]) = v;
  }
  const int q_glob = s0 + (t >> 5);
  unsigned myMask = 0xFFFFFFFFu;
  if (mode == 0) {
    myMask = selmask[q_glob * G_ + g];
    if (t < 16) umasks[t] = selmask[(s0 + t) * G_ + g];
  }
  __syncthreads();
  unsigned um = 0xFFFFFFFFu;
  int mlo = 0;
  const int mhi = (s0 + QT_ - 1) >> 6;
  if (mode == 0) {
    um = 0;
#pragma unroll
    for (int i = 0; i < 16; ++i) um |= umasks[i];
  } else {
    int lo = s0 - (WINW_ - 1); if (lo < 0) lo = 0;
    mlo = lo >> 6;
  }
  const int winlo = (mode == 1) ? (q_glob - (WINW_ - 1)) : 0;
  const int r0 = (t >> 3) * 2;
  const int tok0 = (t & 7) * 8;    // QK token slice == PV dim slice
  float m0 = -INFINITY, m1 = -INFINITY, l0 = 0.f, l1 = 0.f;
  float acc0[8] = {}, acc1[8] = {};

  for (int m = mlo; m <= mhi; ++m) {
    if (!((um >> m) & 1)) continue;
    __syncthreads();                 // protect Kt/Vs/Ps from prior reads
    // ---- stage K (transposed) + V ----
#pragma unroll
    for (int pass = 0; pass < 2; ++pass) {
      int tok = t & 63;
      int dq = (t >> 6) * 4 + pass * 32;
      float4 kk = *reinterpret_cast<const float4*>(
          Kbuf + (size_t)(m * 64 + tok) * 128 + g * 64 + dq);
      Kt[dq + 0][tok] = kk.x; Kt[dq + 1][tok] = kk.y;
      Kt[dq + 2][tok] = kk.z; Kt[dq + 3][tok] = kk.w;
      float4 vv = *reinterpret_cast<const float4*>(
          Vbuf + (size_t)(m * 64 + tok) * 128 + g * 64 + dq);
      *reinterpret_cast<float4*>(&Vs[tok][dq]) = vv;
    }
    __syncthreads();
    // ---- QK^T for 2 rows x 8 tokens ----
    float sc0[8] = {}, sc1[8] = {};
#pragma unroll 16
    for (int d = 0; d < 64; ++d) {
      float qa = Qs[r0][d], qb = Qs[r0 + 1][d];
      float4 k4a = *reinterpret_cast<const float4*>(&Kt[d][tok0]);
      float4 k4b = *reinterpret_cast<const float4*>(&Kt[d][tok0 + 4]);
      float kk[8] = {k4a.x, k4a.y, k4a.z, k4a.w, k4b.x, k4b.y, k4b.z, k4b.w};
#pragma unroll
      for (int j = 0; j < 8; ++j) {
        sc0[j] = fmaf(qa, kk[j], sc0[j]);
        sc1[j] = fmaf(qb, kk[j], sc1[j]);
      }
    }
    // ---- mask + online softmax update ----
    const bool bitok = (mode == 0) ? ((myMask >> m) & 1) : true;
    float tm0 = -INFINITY, tm1 = -INFINITY;
    bool val[8];
#pragma unroll
    for (int j = 0; j < 8; ++j) {
      int tok = m * 64 + tok0 + j;
      val[j] = bitok && (tok <= q_glob) && (tok >= winlo);
      sc0[j] = val[j] ? sc0[j] * SCALE_ : -INFINITY;
      sc1[j] = val[j] ? sc1[j] * SCALE_ : -INFINITY;
      tm0 = fmaxf(tm0, sc0[j]);
      tm1 = fmaxf(tm1, sc1[j]);
    }
#pragma unroll
    for (int off = 1; off < 8; off <<= 1) {
      tm0 = fmaxf(tm0, __shfl_xor(tm0, off));
      tm1 = fmaxf(tm1, __shfl_xor(tm1, off));
    }
    float mn0 = fmaxf(m0, tm0), mn1 = fmaxf(m1, tm1);
    float al0 = (mn0 == -INFINITY) ? 0.f : expf(m0 - mn0);
    float al1 = (mn1 == -INFINITY) ? 0.f : expf(m1 - mn1);
    float p0[8], p1[8];
    float sum0 = 0.f, sum1 = 0.f;
#pragma unroll
    for (int j = 0; j < 8; ++j) {
      p0[j] = val[j] ? expf(sc0[j] - mn0) : 0.f;
      p1[j] = val[j] ? expf(sc1[j] - mn1) : 0.f;
      sum0 += p0[j]; sum1 += p1[j];
    }
#pragma unroll
    for (int off = 1; off < 8; off <<= 1) {
      sum0 += __shfl_xor(sum0, off);
      sum1 += __shfl_xor(sum1, off);
    }
    l0 = l0 * al0 + sum0; l1 = l1 * al1 + sum1;
    m0 = mn0; m1 = mn1;
    *reinterpret_cast<float4*>(&Ps[r0][tok0])     = make_float4(p0[0], p0[1], p0[2], p0[3]);
    *reinterpret_cast<float4*>(&Ps[r0][tok0 + 4]) = make_float4(p0[4], p0[5], p0[6], p0[7]);
    *reinterpret_cast<float4*>(&Ps[r0 + 1][tok0])     = make_float4(p1[0], p1[1], p1[2], p1[3]);
    *reinterpret_cast<float4*>(&Ps[r0 + 1][tok0 + 4]) = make_float4(p1[4], p1[5], p1[6], p1[7]);
    __syncthreads();
    // ---- PV: same 2 rows, dim slice tok0..tok0+7 ----
#pragma unroll
    for (int j = 0; j < 8; ++j) { acc0[j] *= al0; acc1[j] *= al1; }
#pragma unroll 16
    for (int tt = 0; tt < 64; ++tt) {
      float pa = Ps[r0][tt], pb = Ps[r0 + 1][tt];
      float4 v4a = *reinterpret_cast<const float4*>(&Vs[tt][tok0]);
      float4 v4b = *reinterpret_cast<const float4*>(&Vs[tt][tok0 + 4]);
      float vv[8] = {v4a.x, v4a.y, v4a.z, v4a.w, v4b.x, v4b.y, v4b.z, v4b.w};
#pragma unroll
      for (int j = 0; j < 8; ++j) {
        acc0[j] = fmaf(pa, vv[j], acc0[j]);
        acc1[j] = fmaf(pb, vv[j], acc1[j]);
      }
    }
  }
  // ---- final normalize + store ----
  float inv0 = 1.0f / l0, inv1 = 1.0f / l1;
  int q = r0 >> 3, hp0 = r0 & 7;
  size_t base0 = ((size_t)(s0 + q) * 16 + g * 8 + hp0) * 64 + tok0;
  size_t base1 = ((size_t)(s0 + q) * 16 + g * 8 + hp0 + 1) * 64 + tok0;
  *reinterpret_cast<float4*>(Out + base0) =
      make_float4(acc0[0] * inv0, acc0[1] * inv0, acc0[2] * inv0, acc0[3] * inv0);
  *reinterpret_cast<float4*>(Out + base0 + 4) =
      make_float4(acc0[4] * inv0, acc0[5] * inv0, acc0[6] * inv0, acc0[7] * inv0);
  *reinterpret_cast<float4*>(Out + base1) =
      make_float4(acc1[0] * inv1, acc1[1] * inv1, acc1[2] * inv1, acc1[3] * inv1);
  *reinterpret_cast<float4*>(Out + base1 + 4) =
      make_float4(acc1[4] * inv1, acc1[5] * inv1, acc1[6] * inv1, acc1[7] * inv1);
}

// ========================= gate MLP (per (s,g)) =============================
__global__ __launch_bounds__(256) void gate_kernel(const float* __restrict__ Q,
                                                   const float* __restrict__ w1, const float* __restrict__ b1,
                                                   const float* __restrict__ w2, const float* __restrict__ b2,
                                                   float* __restrict__ gates) {
  int id = blockIdx.x * 256 + threadIdx.x;
  if (id >= S_ * G_) return;
  int s = id / G_, g = id % G_;
  float qp[64];
#pragma unroll
  for (int d = 0; d < 64; ++d) {
    float a = 0.f;
#pragma unroll
    for (int hp = 0; hp < 8; ++hp) a += Q[((size_t)(s * 16) + g * 8 + hp) * 64 + d];
    qp[d] = a * 0.125f;
  }
  float h[32];
#pragma unroll
  for (int j = 0; j < 32; ++j) {
    float a = b1[j];
#pragma unroll
    for (int d = 0; d < 64; ++d) a = fmaf(qp[d], w1[j * 64 + d], a);
    h[j] = a / (1.0f + expf(-a));
  }
  float gg[3];
#pragma unroll
  for (int o = 0; o < 3; ++o) {
    float a = b2[o];
#pragma unroll
    for (int j = 0; j < 32; ++j) a = fmaf(h[j], w2[o * 32 + j], a);
    gg[o] = a;
  }
  float mx = fmaxf(gg[0], fmaxf(gg[1], gg[2]));
  float e0 = expf(gg[0] - mx), e1 = expf(gg[1] - mx), e2 = expf(gg[2] - mx);
  float inv = 1.0f / (e0 + e1 + e2);
  float p0 = e0 * inv, p1 = e1 * inv, p2 = e2 * inv;
  int am = (gg[0] >= gg[1] && gg[0] >= gg[2]) ? 0 : (gg[1] >= gg[2] ? 1 : 2);
  float t1 = gg[am];
  float t2 = (am == 0) ? fmaxf(gg[1], gg[2]) : (am == 1) ? fmaxf(gg[0], gg[2]) : fmaxf(gg[0], gg[1]);
  if (t1 - t2 > 50.f) {
    p0 = (am == 0) ? 1.f : 0.f; p1 = (am == 1) ? 1.f : 0.f; p2 = (am == 2) ? 1.f : 0.f;
  }
  gates[id * 3 + 0] = p0; gates[id * 3 + 1] = p1; gates[id * 3 + 2] = p2;
}

// ===================== gated combine of the three outputs ===================
__global__ __launch_bounds__(256) void combine_kernel(const float* __restrict__ Oc,
                                                      const float* __restrict__ Os,
                                                      const float* __restrict__ Ow,
                                                      const float* __restrict__ gates,
                                                      float* __restrict__ Ocomb) {
  int id = blockIdx.x * 256 + threadIdx.x;
  int e = id * 4;
  if (e >= S_ * 1024) return;
  int s = e >> 10, k = e & 1023, g = k >> 9;
  const float* gt = gates + (size_t)(s * G_ + g) * 3;
  float gc = gt[0], gs = gt[1], gw = gt[2];
  float4 c = *reinterpret_cast<const float4*>(Oc + e);
  float4 l = *reinterpret_cast<const float4*>(Os + e);
  float4 w = *reinterpret_cast<const float4*>(Ow + e);
  float4 r;
  r.x = gc * c.x + gs * l.x + gw * w.x;
  r.y = gc * c.y + gs * l.y + gw * w.y;
  r.z = gc * c.z + gs * l.z + gw * w.z;
  r.w = gc * c.w + gs * l.w + gw * w.w;
  *reinterpret_cast<float4*>(Ocomb + e) = r;
}

// ============================================================================
extern "C" void kernel_launch(void* const* d_in, const int* in_sizes, int n_in,
                              void* d_out, int out_size, void* d_ws, size_t ws_size,
                              hipStream_t stream) {
  const float* x     = (const float*)d_in[0];
  const float* W_Q   = (const float*)d_in[1];
  const float* W_Ks  = (const float*)d_in[2];
  const float* W_Vs  = (const float*)d_in[3];
  const float* W_Kw  = (const float*)d_in[4];
  const float* W_Vw  = (const float*)d_in[5];
  const float* W_Kc  = (const float*)d_in[6];
  const float* W_Vc  = (const float*)d_in[7];
  const float* W_out = (const float*)d_in[8];
  const float* fc1w  = (const float*)d_in[9];
  const float* fc1b  = (const float*)d_in[10];
  const float* fc2w  = (const float*)d_in[11];
  const float* fc2b  = (const float*)d_in[12];
  float* out = (float*)d_out;

  float* ws    = (float*)d_ws;
  float* Q     = ws;                                   // S*1024
  float* kv    = Q + (size_t)S_ * 1024;                // 6 * S*128
  float* Kcmp  = kv + (size_t)6 * S_ * 128;            // G*NC*64
  float* Vcmp  = Kcmp + G_ * NC_ * 64;
  float* Ocmp  = Vcmp + G_ * NC_ * 64;                 // S*1024
  float* Osel  = Ocmp + (size_t)S_ * 1024;
  float* Owin  = Osel + (size_t)S_ * 1024;
  float* gates = Owin + (size_t)S_ * 1024;             // S*G*3
  unsigned* selmask = (unsigned*)(gates + S_ * G_ * 3);
  float* Ocomb = Q;  // reuse Q after gate_kernel consumed it

  gemm_nt<<<dim3(1024 / 64, S_ / 64), 256, 0, stream>>>(x, W_Q, Q, S_, 1024, 1024);
  gemm_kv<<<dim3(12, S_ / 64), 256, 0, stream>>>(x, W_Ks, W_Vs, W_Kw, W_Vw, W_Kc, W_Vc, kv, 1024);
  rope_kernel<<<(S_ * 512 + 255) / 256, 256, 0, stream>>>(Q, 1024, S_ * 512);
  rope_kernel<<<(S_ * 64 + 255) / 256, 256, 0, stream>>>(kv + (size_t)0 * S_ * 128, 128, S_ * 64);
  rope_kernel<<<(S_ * 64 + 255) / 256, 256, 0, stream>>>(kv + (size_t)2 * S_ * 128, 128, S_ * 64);
  rope_kernel<<<(S_ * 64 + 255) / 256, 256, 0, stream>>>(kv + (size_t)4 * S_ * 128, 128, S_ * 64);
  compress_kernel<<<dim3(NC_, G_), 64, 0, stream>>>(kv, Kcmp, Vcmp);
  cmp_attn<<<dim3(S_, G_), 256, 0, stream>>>(Q, Kcmp, Vcmp, Ocmp, selmask);
  attn_fused<<<dim3(S_ / QT_, G_, 2), 512, 0, stream>>>(Q, kv, selmask, Osel, Owin);
  gate_kernel<<<(S_ * G_ + 255) / 256, 256, 0, stream>>>(Q, fc1w, fc1b, fc2w, fc2b, gates);
  combine_kernel<<<(S_ * 1024 / 4 + 255) / 256, 256, 0, stream>>>(Ocmp, Osel, Owin, gates, Ocomb);
  gemm_nt<<<dim3(1024 / 64, S_ / 64), 256, 0, stream>>>(Ocomb, W_out, out, S_, 1024, 1024);
}

// Round 5
// 646.429 us; speedup vs baseline: 1.3921x; 1.1104x over previous
//
#include <hip/hip_runtime.h>
#include <math.h>

// ---------------------------------------------------------------------------
// NSA attention forward, fp32 (v3 — QT 16->8: 70KB LDS => 2 blocks/CU,
// heavy-first block order for tail balance).
// ---------------------------------------------------------------------------

#define S_    1536
#define DIM_  1024
#define G_    2
#define HPG_  8
#define H_    16
#define DK_   64
#define NC_   95
#define NB_   24
#define NSEL_ 16
#define WINW_ 512
#define SCALE_ 0.125f
#define QT_   8

// ======================= generic GEMM: C[m][n] = sum_k A[m][k]*B[n][k] ======
__global__ __launch_bounds__(256) void gemm_nt(const float* __restrict__ A,
                                               const float* __restrict__ B,
                                               float* __restrict__ C,
                                               int M, int N, int K) {
  __shared__ float As[16][68];
  __shared__ float Bs[16][68];
  int bn = blockIdx.x * 64, bm = blockIdx.y * 64;
  int t = threadIdx.x;
  int tn = (t & 15) * 4, tm = (t >> 4) * 4;
  float acc[4][4] = {};
  const float* Ab = A + (size_t)bm * K;
  const float* Bb = B + (size_t)bn * K;
  int row = t >> 2, kq = t & 3;
  for (int k0 = 0; k0 < K; k0 += 16) {
    float4 av = *reinterpret_cast<const float4*>(Ab + (size_t)row * K + k0 + kq * 4);
    float4 bv = *reinterpret_cast<const float4*>(Bb + (size_t)row * K + k0 + kq * 4);
    As[kq*4+0][row] = av.x; As[kq*4+1][row] = av.y; As[kq*4+2][row] = av.z; As[kq*4+3][row] = av.w;
    Bs[kq*4+0][row] = bv.x; Bs[kq*4+1][row] = bv.y; Bs[kq*4+2][row] = bv.z; Bs[kq*4+3][row] = bv.w;
    __syncthreads();
#pragma unroll
    for (int kk = 0; kk < 16; ++kk) {
      float4 a4 = *reinterpret_cast<const float4*>(&As[kk][tm]);
      float4 b4 = *reinterpret_cast<const float4*>(&Bs[kk][tn]);
      float av_[4] = {a4.x, a4.y, a4.z, a4.w};
      float bv_[4] = {b4.x, b4.y, b4.z, b4.w};
#pragma unroll
      for (int i = 0; i < 4; ++i)
#pragma unroll
        for (int j = 0; j < 4; ++j) acc[i][j] = fmaf(av_[i], bv_[j], acc[i][j]);
    }
    __syncthreads();
  }
#pragma unroll
  for (int i = 0; i < 4; ++i) {
    *reinterpret_cast<float4*>(C + (size_t)(bm + tm + i) * N + bn + tn) =
        make_float4(acc[i][0], acc[i][1], acc[i][2], acc[i][3]);
  }
}

// ============ fused KV projections: 6 weights, out layout [proj][S][128] ====
__global__ __launch_bounds__(256) void gemm_kv(const float* __restrict__ A,
                                               const float* __restrict__ w0, const float* __restrict__ w1,
                                               const float* __restrict__ w2, const float* __restrict__ w3,
                                               const float* __restrict__ w4, const float* __restrict__ w5,
                                               float* __restrict__ kvout, int K) {
  __shared__ float As[16][68];
  __shared__ float Bs[16][68];
  int jb = blockIdx.x;              // 0..11
  int proj = jb >> 1, nc0 = (jb & 1) * 64;
  const float* B;
  switch (proj) { case 0: B = w0; break; case 1: B = w1; break; case 2: B = w2; break;
                  case 3: B = w3; break; case 4: B = w4; break; default: B = w5; }
  float* C = kvout + (size_t)proj * (S_ * 128);
  int bm = blockIdx.y * 64;
  int t = threadIdx.x;
  int tn = (t & 15) * 4, tm = (t >> 4) * 4;
  float acc[4][4] = {};
  const float* Ab = A + (size_t)bm * K;
  const float* Bb = B + (size_t)nc0 * K;
  int row = t >> 2, kq = t & 3;
  for (int k0 = 0; k0 < K; k0 += 16) {
    float4 av = *reinterpret_cast<const float4*>(Ab + (size_t)row * K + k0 + kq * 4);
    float4 bv = *reinterpret_cast<const float4*>(Bb + (size_t)row * K + k0 + kq * 4);
    As[kq*4+0][row] = av.x; As[kq*4+1][row] = av.y; As[kq*4+2][row] = av.z; As[kq*4+3][row] = av.w;
    Bs[kq*4+0][row] = bv.x; Bs[kq*4+1][row] = bv.y; Bs[kq*4+2][row] = bv.z; Bs[kq*4+3][row] = bv.w;
    __syncthreads();
#pragma unroll
    for (int kk = 0; kk < 16; ++kk) {
      float4 a4 = *reinterpret_cast<const float4*>(&As[kk][tm]);
      float4 b4 = *reinterpret_cast<const float4*>(&Bs[kk][tn]);
      float av_[4] = {a4.x, a4.y, a4.z, a4.w};
      float bv_[4] = {b4.x, b4.y, b4.z, b4.w};
#pragma unroll
      for (int i = 0; i < 4; ++i)
#pragma unroll
        for (int j = 0; j < 4; ++j) acc[i][j] = fmaf(av_[i], bv_[j], acc[i][j]);
    }
    __syncthreads();
  }
#pragma unroll
  for (int i = 0; i < 4; ++i) {
    *reinterpret_cast<float4*>(C + (size_t)(bm + tm + i) * 128 + nc0 + tn) =
        make_float4(acc[i][0], acc[i][1], acc[i][2], acc[i][3]);
  }
}

// =========================== RoPE (in place) ================================
__global__ __launch_bounds__(256) void rope_kernel(float* __restrict__ p, int ncols, int total_pairs) {
  int id = blockIdx.x * 256 + threadIdx.x;
  if (id >= total_pairs) return;
  int ppr = ncols >> 1;
  int row = id / ppr, rem = id % ppr;
  int head = rem >> 5, jj = rem & 31;
  float inv = 1.0f / powf(10000.0f, (float)jj * (1.0f / 32.0f));
  float ang = (float)row * inv;
  float sn, cs;
  sincosf(ang, &sn, &cs);
  float* q = p + (size_t)row * ncols + head * 64 + jj;
  float x1 = q[0], x2 = q[32];
  q[0]  = x1 * cs - x2 * sn;
  q[32] = x2 * cs + x1 * sn;
}

// ================== compression: mean over L=32 window, stride 16 ===========
__global__ __launch_bounds__(64) void compress_kernel(const float* __restrict__ kv,
                                                      float* __restrict__ Kcmp,
                                                      float* __restrict__ Vcmp) {
  int c = blockIdx.x, g = blockIdx.y, d = threadIdx.x;
  const float* Kc = kv + (size_t)4 * (S_ * 128);
  const float* Vc = kv + (size_t)5 * (S_ * 128);
  float sk = 0.f, sv = 0.f;
  int base = c * 16;
#pragma unroll
  for (int l = 0; l < 32; ++l) {
    int s = base + l;
    sk += Kc[(size_t)s * 128 + g * 64 + d];
    sv += Vc[(size_t)s * 128 + g * 64 + d];
  }
  Kcmp[(g * NC_ + c) * 64 + d] = sk * (1.0f / 32.0f);
  Vcmp[(g * NC_ + c) * 64 + d] = sv * (1.0f / 32.0f);
}

// ====== compressed attention + p_grp + top-16 block selection ===============
__global__ __launch_bounds__(256) void cmp_attn(const float* __restrict__ Q,
                                                const float* __restrict__ Kcmp,
                                                const float* __restrict__ Vcmp,
                                                float* __restrict__ Ocmp,
                                                unsigned* __restrict__ selmask) {
  int s = blockIdx.x, g = blockIdx.y;
  __shared__ float Ks[NC_][65];
  __shared__ float Vs[NC_][65];
  __shared__ float Qs[8][64];
  __shared__ float Ps[8][NC_];
  __shared__ float pg[NB_];
  int t = threadIdx.x;
  for (int j = t; j < NC_ * 64; j += 256) {
    int c = j >> 6, d = j & 63;
    Ks[c][d] = Kcmp[(g * NC_ + c) * 64 + d];
    Vs[c][d] = Vcmp[(g * NC_ + c) * 64 + d];
  }
  for (int j = t; j < 512; j += 256) {
    int hp = j >> 6, d = j & 63;
    Qs[hp][d] = Q[((size_t)(s * 16) + g * 8 + hp) * 64 + d];
  }
  __syncthreads();
  int clim = (s >= 31) ? ((s - 31) >> 4) : -1;
  if (clim > NC_ - 1) clim = NC_ - 1;
  for (int j = t; j < 8 * NC_; j += 256) {
    int hp = j / NC_, c = j % NC_;
    float acc = 0.f;
#pragma unroll
    for (int d = 0; d < 64; ++d) acc = fmaf(Qs[hp][d], Ks[c][d], acc);
    Ps[hp][c] = acc * SCALE_;
  }
  __syncthreads();
  int wave = t >> 6, lane = t & 63;
#pragma unroll
  for (int rep = 0; rep < 2; ++rep) {
    int hp = wave + rep * 4;
    float s0 = (lane <= clim) ? Ps[hp][lane] : -INFINITY;
    float s1 = (lane + 64 <= clim) ? Ps[hp][lane + 64] : -INFINITY;
    float mx = fmaxf(s0, s1);
    for (int off = 32; off; off >>= 1) mx = fmaxf(mx, __shfl_xor(mx, off));
    float e0 = (lane <= clim) ? expf(s0 - mx) : 0.f;
    float e1 = (lane + 64 <= clim) ? expf(s1 - mx) : 0.f;
    float sm = e0 + e1;
    for (int off = 32; off; off >>= 1) sm += __shfl_xor(sm, off);
    float invs = (clim >= 0) ? 1.0f / sm : 0.f;
    Ps[hp][lane] = e0 * invs;
    if (lane + 64 < NC_) Ps[hp][lane + 64] = e1 * invs;
  }
  __syncthreads();
  for (int j = t; j < 512; j += 256) {
    int hp = j >> 6, d = j & 63;
    float acc = 0.f;
    for (int c = 0; c <= clim; ++c) acc = fmaf(Ps[hp][c], Vs[c][d], acc);
    Ocmp[((size_t)(s * 16) + g * 8 + hp) * 64 + d] = acc;
  }
  if (t < NB_) {
    int m = t;
    float a = 0.f;
    int clo = (4 * m - 1 < 0) ? 0 : 4 * m - 1;
    int chi = (4 * m + 3 > NC_ - 1) ? NC_ - 1 : 4 * m + 3;
    for (int c = clo; c <= chi; ++c) {
      int lo = c * 16 > m * 64 ? c * 16 : m * 64;
      int hi = (c * 16 + 32) < (m * 64 + 64) ? (c * 16 + 32) : (m * 64 + 64);
      int ov = hi - lo; if (ov < 0) ov = 0;
      float w = (float)ov * (1.0f / 32.0f);
      float sh = 0.f;
#pragma unroll
      for (int hp = 0; hp < 8; ++hp) sh += Ps[hp][c];
      a = fmaf(sh, w, a);
    }
    pg[m] = a;
  }
  __syncthreads();
  if (t == 0) {
    float sc[NB_];
    int blk = s >> 6;
    for (int m = 0; m < NB_; ++m) {
      float v = pg[m] + ((m == 0 || m == blk) ? 1e6f : 0.f);
      if (s < m * 64) v = -1e9f;
      sc[m] = v;
    }
    unsigned mask = 0;
    for (int it = 0; it < NSEL_; ++it) {
      int best = 0; float bv = -INFINITY;
      for (int m = 0; m < NB_; ++m)
        if (!((mask >> m) & 1) && sc[m] > bv) { bv = sc[m]; best = m; }
      mask |= (1u << best);
    }
    selmask[s * G_ + g] = mask;
  }
}

// ============== fused sel/win attention, 8-query tiles, flash-style =========
// grid (S/QT, G, 2): z=0 selected-blocks mode, z=1 sliding-window mode.
// 256 threads; tb reversed so heaviest blocks (largest s0) launch first.
// Thread t owns rows r0=2*(t>>3), r0+1 (query q=t>>5) and token/dim slice
// (t&7)*8..+7.  LDS ~70 KB => 2 blocks/CU.
__global__ __launch_bounds__(256) void attn_fused(const float* __restrict__ Qg,
                                                  const float* __restrict__ kv,
                                                  const unsigned* __restrict__ selmask,
                                                  float* __restrict__ Osel,
                                                  float* __restrict__ Owin) {
  const int tb = (int)gridDim.x - 1 - (int)blockIdx.x;   // heavy-first
  const int g = blockIdx.y, mode = blockIdx.z;
  const int s0 = tb * QT_;
  const float* Kbuf = kv + (size_t)(mode ? 2 : 0) * (S_ * 128);
  const float* Vbuf = kv + (size_t)(mode ? 3 : 1) * (S_ * 128);
  float* Out = mode ? Owin : Osel;

  __shared__ float Qs[64][68];
  __shared__ float Ps[64][68];
  __shared__ float Kt[64][68];   // transposed: Kt[d][tok]
  __shared__ float Vs[64][68];   // Vs[tok][d]
  __shared__ unsigned umasks[8];

  const int t = threadIdx.x;
  // ---- stage Q tile (64 rows x 64) ----
#pragma unroll
  for (int k = 0; k < 4; ++k) {
    int qid = t + k * 256;           // 0..1023 quads
    int row = qid >> 4, c4 = qid & 15;
    int q = row >> 3, hp = row & 7;
    float4 v = *reinterpret_cast<const float4*>(
        Qg + ((size_t)(s0 + q) * 16 + g * 8 + hp) * 64 + c4 * 4);
    *reinterpret_cast<float4*>(&Qs[row][c4 * 4]) = v;
  }
  const int q_glob = s0 + (t >> 5);
  unsigned myMask = 0xFFFFFFFFu;
  if (mode == 0) {
    myMask = selmask[q_glob * G_ + g];
    if (t < 8) umasks[t] = selmask[(s0 + t) * G_ + g];
  }
  __syncthreads();
  unsigned um = 0xFFFFFFFFu;
  int mlo = 0;
  const int mhi = (s0 + QT_ - 1) >> 6;
  if (mode == 0) {
    um = 0;
#pragma unroll
    for (int i = 0; i < 8; ++i) um |= umasks[i];
  } else {
    int lo = s0 - (WINW_ - 1); if (lo < 0) lo = 0;
    mlo = lo >> 6;
  }
  const int winlo = (mode == 1) ? (q_glob - (WINW_ - 1)) : 0;
  const int r0 = (t >> 3) * 2;
  const int tok0 = (t & 7) * 8;    // QK token slice == PV dim slice
  float m0 = -INFINITY, m1 = -INFINITY, l0 = 0.f, l1 = 0.f;
  float acc0[8] = {}, acc1[8] = {};

  for (int m = mlo; m <= mhi; ++m) {
    if (!((um >> m) & 1)) continue;
    __syncthreads();                 // protect Kt/Vs/Ps from prior reads
    // ---- stage K (transposed) + V ----
#pragma unroll
    for (int pass = 0; pass < 4; ++pass) {
      int tok = t & 63;
      int dq = (t >> 6) * 4 + pass * 16;
      float4 kk = *reinterpret_cast<const float4*>(
          Kbuf + (size_t)(m * 64 + tok) * 128 + g * 64 + dq);
      Kt[dq + 0][tok] = kk.x; Kt[dq + 1][tok] = kk.y;
      Kt[dq + 2][tok] = kk.z; Kt[dq + 3][tok] = kk.w;
      float4 vv = *reinterpret_cast<const float4*>(
          Vbuf + (size_t)(m * 64 + tok) * 128 + g * 64 + dq);
      *reinterpret_cast<float4*>(&Vs[tok][dq]) = vv;
    }
    __syncthreads();
    // ---- QK^T for 2 rows x 8 tokens ----
    float sc0[8] = {}, sc1[8] = {};
#pragma unroll 16
    for (int d = 0; d < 64; ++d) {
      float qa = Qs[r0][d], qb = Qs[r0 + 1][d];
      float4 k4a = *reinterpret_cast<const float4*>(&Kt[d][tok0]);
      float4 k4b = *reinterpret_cast<const float4*>(&Kt[d][tok0 + 4]);
      float kk[8] = {k4a.x, k4a.y, k4a.z, k4a.w, k4b.x, k4b.y, k4b.z, k4b.w};
#pragma unroll
      for (int j = 0; j < 8; ++j) {
        sc0[j] = fmaf(qa, kk[j], sc0[j]);
        sc1[j] = fmaf(qb, kk[j], sc1[j]);
      }
    }
    // ---- mask + online softmax update ----
    const bool bitok = (mode == 0) ? ((myMask >> m) & 1) : true;
    float tm0 = -INFINITY, tm1 = -INFINITY;
    bool val[8];
#pragma unroll
    for (int j = 0; j < 8; ++j) {
      int tok = m * 64 + tok0 + j;
      val[j] = bitok && (tok <= q_glob) && (tok >= winlo);
      sc0[j] = val[j] ? sc0[j] * SCALE_ : -INFINITY;
      sc1[j] = val[j] ? sc1[j] * SCALE_ : -INFINITY;
      tm0 = fmaxf(tm0, sc0[j]);
      tm1 = fmaxf(tm1, sc1[j]);
    }
#pragma unroll
    for (int off = 1; off < 8; off <<= 1) {
      tm0 = fmaxf(tm0, __shfl_xor(tm0, off));
      tm1 = fmaxf(tm1, __shfl_xor(tm1, off));
    }
    float mn0 = fmaxf(m0, tm0), mn1 = fmaxf(m1, tm1);
    float al0 = (mn0 == -INFINITY) ? 0.f : expf(m0 - mn0);
    float al1 = (mn1 == -INFINITY) ? 0.f : expf(m1 - mn1);
    float p0[8], p1[8];
    float sum0 = 0.f, sum1 = 0.f;
#pragma unroll
    for (int j = 0; j < 8; ++j) {
      p0[j] = val[j] ? expf(sc0[j] - mn0) : 0.f;
      p1[j] = val[j] ? expf(sc1[j] - mn1) : 0.f;
      sum0 += p0[j]; sum1 += p1[j];
    }
#pragma unroll
    for (int off = 1; off < 8; off <<= 1) {
      sum0 += __shfl_xor(sum0, off);
      sum1 += __shfl_xor(sum1, off);
    }
    l0 = l0 * al0 + sum0; l1 = l1 * al1 + sum1;
    m0 = mn0; m1 = mn1;
    *reinterpret_cast<float4*>(&Ps[r0][tok0])     = make_float4(p0[0], p0[1], p0[2], p0[3]);
    *reinterpret_cast<float4*>(&Ps[r0][tok0 + 4]) = make_float4(p0[4], p0[5], p0[6], p0[7]);
    *reinterpret_cast<float4*>(&Ps[r0 + 1][tok0])     = make_float4(p1[0], p1[1], p1[2], p1[3]);
    *reinterpret_cast<float4*>(&Ps[r0 + 1][tok0 + 4]) = make_float4(p1[4], p1[5], p1[6], p1[7]);
    __syncthreads();
    // ---- PV: same 2 rows, dim slice tok0..tok0+7 ----
#pragma unroll
    for (int j = 0; j < 8; ++j) { acc0[j] *= al0; acc1[j] *= al1; }
#pragma unroll 16
    for (int tt = 0; tt < 64; ++tt) {
      float pa = Ps[r0][tt], pb = Ps[r0 + 1][tt];
      float4 v4a = *reinterpret_cast<const float4*>(&Vs[tt][tok0]);
      float4 v4b = *reinterpret_cast<const float4*>(&Vs[tt][tok0 + 4]);
      float vv[8] = {v4a.x, v4a.y, v4a.z, v4a.w, v4b.x, v4b.y, v4b.z, v4b.w};
#pragma unroll
      for (int j = 0; j < 8; ++j) {
        acc0[j] = fmaf(pa, vv[j], acc0[j]);
        acc1[j] = fmaf(pb, vv[j], acc1[j]);
      }
    }
  }
  // ---- final normalize + store ----
  float inv0 = 1.0f / l0, inv1 = 1.0f / l1;
  int q = r0 >> 3, hp0 = r0 & 7;
  size_t base0 = ((size_t)(s0 + q) * 16 + g * 8 + hp0) * 64 + tok0;
  size_t base1 = ((size_t)(s0 + q) * 16 + g * 8 + hp0 + 1) * 64 + tok0;
  *reinterpret_cast<float4*>(Out + base0) =
      make_float4(acc0[0] * inv0, acc0[1] * inv0, acc0[2] * inv0, acc0[3] * inv0);
  *reinterpret_cast<float4*>(Out + base0 + 4) =
      make_float4(acc0[4] * inv0, acc0[5] * inv0, acc0[6] * inv0, acc0[7] * inv0);
  *reinterpret_cast<float4*>(Out + base1) =
      make_float4(acc1[0] * inv1, acc1[1] * inv1, acc1[2] * inv1, acc1[3] * inv1);
  *reinterpret_cast<float4*>(Out + base1 + 4) =
      make_float4(acc1[4] * inv1, acc1[5] * inv1, acc1[6] * inv1, acc1[7] * inv1);
}

// ========================= gate MLP (per (s,g)) =============================
__global__ __launch_bounds__(256) void gate_kernel(const float* __restrict__ Q,
                                                   const float* __restrict__ w1, const float* __restrict__ b1,
                                                   const float* __restrict__ w2, const float* __restrict__ b2,
                                                   float* __restrict__ gates) {
  int id = blockIdx.x * 256 + threadIdx.x;
  if (id >= S_ * G_) return;
  int s = id / G_, g = id % G_;
  float qp[64];
#pragma unroll
  for (int d = 0; d < 64; ++d) {
    float a = 0.f;
#pragma unroll
    for (int hp = 0; hp < 8; ++hp) a += Q[((size_t)(s * 16) + g * 8 + hp) * 64 + d];
    qp[d] = a * 0.125f;
  }
  float h[32];
#pragma unroll
  for (int j = 0; j < 32; ++j) {
    float a = b1[j];
#pragma unroll
    for (int d = 0; d < 64; ++d) a = fmaf(qp[d], w1[j * 64 + d], a);
    h[j] = a / (1.0f + expf(-a));
  }
  float gg[3];
#pragma unroll
  for (int o = 0; o < 3; ++o) {
    float a = b2[o];
#pragma unroll
    for (int j = 0; j < 32; ++j) a = fmaf(h[j], w2[o * 32 + j], a);
    gg[o] = a;
  }
  float mx = fmaxf(gg[0], fmaxf(gg[1], gg[2]));
  float e0 = expf(gg[0] - mx), e1 = expf(gg[1] - mx), e2 = expf(gg[2] - mx);
  float inv = 1.0f / (e0 + e1 + e2);
  float p0 = e0 * inv, p1 = e1 * inv, p2 = e2 * inv;
  int am = (gg[0] >= gg[1] && gg[0] >= gg[2]) ? 0 : (gg[1] >= gg[2] ? 1 : 2);
  float t1 = gg[am];
  float t2 = (am == 0) ? fmaxf(gg[1], gg[2]) : (am == 1) ? fmaxf(gg[0], gg[2]) : fmaxf(gg[0], gg[1]);
  if (t1 - t2 > 50.f) {
    p0 = (am == 0) ? 1.f : 0.f; p1 = (am == 1) ? 1.f : 0.f; p2 = (am == 2) ? 1.f : 0.f;
  }
  gates[id * 3 + 0] = p0; gates[id * 3 + 1] = p1; gates[id * 3 + 2] = p2;
}

// ===================== gated combine of the three outputs ===================
__global__ __launch_bounds__(256) void combine_kernel(const float* __restrict__ Oc,
                                                      const float* __restrict__ Os,
                                                      const float* __restrict__ Ow,
                                                      const float* __restrict__ gates,
                                                      float* __restrict__ Ocomb) {
  int id = blockIdx.x * 256 + threadIdx.x;
  int e = id * 4;
  if (e >= S_ * 1024) return;
  int s = e >> 10, k = e & 1023, g = k >> 9;
  const float* gt = gates + (size_t)(s * G_ + g) * 3;
  float gc = gt[0], gs = gt[1], gw = gt[2];
  float4 c = *reinterpret_cast<const float4*>(Oc + e);
  float4 l = *reinterpret_cast<const float4*>(Os + e);
  float4 w = *reinterpret_cast<const float4*>(Ow + e);
  float4 r;
  r.x = gc * c.x + gs * l.x + gw * w.x;
  r.y = gc * c.y + gs * l.y + gw * w.y;
  r.z = gc * c.z + gs * l.z + gw * w.z;
  r.w = gc * c.w + gs * l.w + gw * w.w;
  *reinterpret_cast<float4*>(Ocomb + e) = r;
}

// ============================================================================
extern "C" void kernel_launch(void* const* d_in, const int* in_sizes, int n_in,
                              void* d_out, int out_size, void* d_ws, size_t ws_size,
                              hipStream_t stream) {
  const float* x     = (const float*)d_in[0];
  const float* W_Q   = (const float*)d_in[1];
  const float* W_Ks  = (const float*)d_in[2];
  const float* W_Vs  = (const float*)d_in[3];
  const float* W_Kw  = (const float*)d_in[4];
  const float* W_Vw  = (const float*)d_in[5];
  const float* W_Kc  = (const float*)d_in[6];
  const float* W_Vc  = (const float*)d_in[7];
  const float* W_out = (const float*)d_in[8];
  const float* fc1w  = (const float*)d_in[9];
  const float* fc1b  = (const float*)d_in[10];
  const float* fc2w  = (const float*)d_in[11];
  const float* fc2b  = (const float*)d_in[12];
  float* out = (float*)d_out;

  float* ws    = (float*)d_ws;
  float* Q     = ws;                                   // S*1024
  float* kv    = Q + (size_t)S_ * 1024;                // 6 * S*128
  float* Kcmp  = kv + (size_t)6 * S_ * 128;            // G*NC*64
  float* Vcmp  = Kcmp + G_ * NC_ * 64;
  float* Ocmp  = Vcmp + G_ * NC_ * 64;                 // S*1024
  float* Osel  = Ocmp + (size_t)S_ * 1024;
  float* Owin  = Osel + (size_t)S_ * 1024;
  float* gates = Owin + (size_t)S_ * 1024;             // S*G*3
  unsigned* selmask = (unsigned*)(gates + S_ * G_ * 3);
  float* Ocomb = Q;  // reuse Q after gate_kernel consumed it

  gemm_nt<<<dim3(1024 / 64, S_ / 64), 256, 0, stream>>>(x, W_Q, Q, S_, 1024, 1024);
  gemm_kv<<<dim3(12, S_ / 64), 256, 0, stream>>>(x, W_Ks, W_Vs, W_Kw, W_Vw, W_Kc, W_Vc, kv, 1024);
  rope_kernel<<<(S_ * 512 + 255) / 256, 256, 0, stream>>>(Q, 1024, S_ * 512);
  rope_kernel<<<(S_ * 64 + 255) / 256, 256, 0, stream>>>(kv + (size_t)0 * S_ * 128, 128, S_ * 64);
  rope_kernel<<<(S_ * 64 + 255) / 256, 256, 0, stream>>>(kv + (size_t)2 * S_ * 128, 128, S_ * 64);
  rope_kernel<<<(S_ * 64 + 255) / 256, 256, 0, stream>>>(kv + (size_t)4 * S_ * 128, 128, S_ * 64);
  compress_kernel<<<dim3(NC_, G_), 64, 0, stream>>>(kv, Kcmp, Vcmp);
  cmp_attn<<<dim3(S_, G_), 256, 0, stream>>>(Q, Kcmp, Vcmp, Ocmp, selmask);
  attn_fused<<<dim3(S_ / QT_, G_, 2), 256, 0, stream>>>(Q, kv, selmask, Osel, Owin);
  gate_kernel<<<(S_ * G_ + 255) / 256, 256, 0, stream>>>(Q, fc1w, fc1b, fc2w, fc2b, gates);
  combine_kernel<<<(S_ * 1024 / 4 + 255) / 256, 256, 0, stream>>>(Ocmp, Osel, Owin, gates, Ocomb);
  gemm_nt<<<dim3(1024 / 64, S_ / 64), 256, 0, stream>>>(Ocomb, W_out, out, S_, 1024, 1024);
}